// Round 5
// baseline (317.543 us; speedup 1.0000x reference)
//
#include <hip/hip_runtime.h>
#include <hip/hip_bf16.h>

#define UU 2048
#define DM 32
#define TB 128   // tile edge
#define NB 16    // batch
#define NP 3     // pairs

typedef short short8_t __attribute__((ext_vector_type(8)));
typedef float float4_t __attribute__((ext_vector_type(4)));

// split x into bf16 hi (truncate) + bf16 lo (truncate of remainder).
// hi+lo carries ~24 bits of mantissa; dropped lo*lo term in the dot is
// ~2^-16 relative -> dot abs err ~5e-4 vs absmax threshold 7e-2.
__device__ inline void split8(const float4 x0, const float4 x1, short8_t& h,
                              short8_t& lo) {
  float xs[8] = {x0.x, x0.y, x0.z, x0.w, x1.x, x1.y, x1.z, x1.w};
#pragma unroll
  for (int i = 0; i < 8; ++i) {
    unsigned u = __float_as_uint(xs[i]);
    h[i] = (short)(u >> 16);
    float hif = __uint_as_float(u & 0xffff0000u);
    lo[i] = (short)(__float_as_uint(xs[i] - hif) >> 16);
  }
}

// ---------------------------------------------------------------------------
// Stage 1 (MFMA bf16x3): for each (pair, b) compute
//   S1[j] = sum_i exp(f1_i . f2_j),  S2[i] = sum_j exp(f1_i . f2_j)
// 128x128 region/block, 4 waves; wave w covers rows [w*32, w*32+32).
// A-fragments are wave-private -> loaded straight from global (L2) and
// split in registers; only the shared B tile goes through LDS (22.5 KB).
// __launch_bounds__(256,4): VGPR cap 128. (256,6) capped at ~85 and SPILLED:
// VGPR_Count 40, WRITE_SIZE 30->202 MB scratch, stage1 93->144 us. Cap 128
// fits the ~100 live regs (a-frags 16 + acc 16 + rowp/colp 16 + b-frags 8
// + staging/addr) with 4 blocks/CU.
// Per 16x16 tile: 3x mfma_f32_16x16x32_bf16 split into two independent
// accumulator chains (hh | hl+lh) for MFMA ILP; exp arg = c0+c1.
// C/D layout: col=lane&15, row=(lane>>4)*4+reg  [m89-verified].
// LDS rows padded to 40 shorts (80B): 16B-aligned b128 frags, <=2-way banks.
// ---------------------------------------------------------------------------
__global__ __launch_bounds__(256, 4) void stage1_sums(
    const float* __restrict__ a, const float* __restrict__ v,
    const float* __restrict__ l, float* __restrict__ S1,
    float* __restrict__ S2) {
  const int p = blockIdx.z >> 4;   // pair 0..2
  const int b = blockIdx.z & 15;   // batch
  const float* f1 = (p == 2) ? v : a;   // p0:(a,v) p1:(a,l) p2:(v,l)
  const float* f2 = (p == 0) ? v : l;
  f1 += (size_t)b * UU * DM;
  f2 += (size_t)b * UU * DM;
  const int i0 = blockIdx.y * TB;
  const int j0 = blockIdx.x * TB;

  __shared__ __align__(16) short Bh[TB][40];
  __shared__ __align__(16) short Bl[TB][40];
  __shared__ float ldsC[4][TB];

  const int t = threadIdx.x;
  const int lane = t & 63, w = t >> 6;
  const int lm = lane & 15, lq = lane >> 4;
  const int k0 = lq * 8;

  // Issue the wave-private A loads first (overlap with B staging below).
  float4 a_raw[2][2];
#pragma unroll
  for (int rt = 0; rt < 2; ++rt) {
    const float* src = f1 + (size_t)(i0 + w * 32 + rt * 16 + lm) * DM + k0;
    a_raw[rt][0] = *(const float4*)src;
    a_raw[rt][1] = *(const float4*)(src + 4);
  }

  // Stage the shared B tile (hi/lo bf16), 8 consecutive floats per unit.
#pragma unroll
  for (int pass = 0; pass < 2; ++pass) {
    int f8 = pass * 256 + t;     // 0..511 (8-float unit)
    int row = f8 >> 2;           // 0..127
    int col = (f8 & 3) * 8;      // 0,8,16,24
    const float* src = f2 + (size_t)(j0 + row) * DM + col;
    short8_t h, lo;
    split8(*(const float4*)src, *(const float4*)(src + 4), h, lo);
    *(short8_t*)&Bh[row][col] = h;
    *(short8_t*)&Bl[row][col] = lo;
  }

  // Split A in registers.
  short8_t a_h[2], a_l[2];
#pragma unroll
  for (int rt = 0; rt < 2; ++rt)
    split8(a_raw[rt][0], a_raw[rt][1], a_h[rt], a_l[rt]);
  __syncthreads();

  float rowp[2][4];
  float colp[8];
#pragma unroll
  for (int rt = 0; rt < 2; ++rt)
#pragma unroll
    for (int r = 0; r < 4; ++r) rowp[rt][r] = 0.f;
#pragma unroll
  for (int ct = 0; ct < 8; ++ct) colp[ct] = 0.f;

#pragma unroll
  for (int ct = 0; ct < 8; ++ct) {
    int n = ct * 16 + lm;
    short8_t b_h = *(short8_t*)&Bh[n][k0];
    short8_t b_l = *(short8_t*)&Bl[n][k0];
#pragma unroll
    for (int rt = 0; rt < 2; ++rt) {
      float4_t c0 = {0.f, 0.f, 0.f, 0.f};
      float4_t c1 = {0.f, 0.f, 0.f, 0.f};
      c0 = __builtin_amdgcn_mfma_f32_16x16x32_bf16(a_h[rt], b_h, c0, 0, 0, 0);
      c1 = __builtin_amdgcn_mfma_f32_16x16x32_bf16(a_h[rt], b_l, c1, 0, 0, 0);
      c1 = __builtin_amdgcn_mfma_f32_16x16x32_bf16(a_l[rt], b_h, c1, 0, 0, 0);
      float e0 = __expf(c0[0] + c1[0]);
      float e1 = __expf(c0[1] + c1[1]);
      float e2 = __expf(c0[2] + c1[2]);
      float e3 = __expf(c0[3] + c1[3]);
      rowp[rt][0] += e0;
      rowp[rt][1] += e1;
      rowp[rt][2] += e2;
      rowp[rt][3] += e3;
      colp[ct] += (e0 + e1) + (e2 + e3);
    }
  }

  const size_t base = (size_t)(p * NB + b) * UU;

  // Row (i) sums: reduce across the 16 lanes of each quarter (cols 0..15)
#pragma unroll
  for (int rt = 0; rt < 2; ++rt)
#pragma unroll
    for (int r = 0; r < 4; ++r) {
      float vv = rowp[rt][r];
      vv += __shfl_xor(vv, 1, 64);
      vv += __shfl_xor(vv, 2, 64);
      vv += __shfl_xor(vv, 4, 64);
      vv += __shfl_xor(vv, 8, 64);
      if (lm == 0)
        atomicAdd(&S2[base + i0 + w * 32 + rt * 16 + lq * 4 + r], vv);
    }

  // Col (j) sums: reduce across quarters (rows), then across waves via LDS
#pragma unroll
  for (int ct = 0; ct < 8; ++ct) {
    float vv = colp[ct];
    vv += __shfl_xor(vv, 16, 64);
    vv += __shfl_xor(vv, 32, 64);
    if (lane < 16) ldsC[w][ct * 16 + lane] = vv;
  }
  __syncthreads();
  if (t < TB) {
    float s = ldsC[0][t] + ldsC[1][t] + ldsC[2][t] + ldsC[3][t];
    atomicAdd(&S1[base + j0 + t], s);
  }
}

// ---------------------------------------------------------------------------
// Stage 2: per (pair, b, dir, chunk-of-256-rows) compute the partial 32-vec
//   dir0: O1_part = sum_{j in chunk} exp(f1_0 . f2_j)/S1[j] * f2_j
//   dir1: O2_part = sum_{i in chunk} exp(f1_i . f2_0)/S2[i] * f1_i
// Plain store into OOpart[pd][chunk][32] (no atomics -> no memset needed).
// qrow scaling happens in stage3.
// ---------------------------------------------------------------------------
__global__ __launch_bounds__(256) void stage2_O(
    const float* __restrict__ a, const float* __restrict__ v,
    const float* __restrict__ l, const float* __restrict__ S1,
    const float* __restrict__ S2, float* __restrict__ OOpart) {
  const int idx = blockIdx.x;
  const int chunk = idx & 7;
  const int pd = idx >> 3;       // (pb, dir) flat
  const int dir = pd & 1;
  const int pb = pd >> 1;
  const int p = pb >> 4, b = pb & 15;
  const float* f1 = (p == 2) ? v : a;
  const float* f2 = (p == 0) ? v : l;
  f1 += (size_t)b * UU * DM;
  f2 += (size_t)b * UU * DM;
  const float* qrow = (dir == 0) ? f1 : f2;  // row 0 of the "query" side
  const float* rows = (dir == 0) ? f2 : f1;
  const float* den = ((dir == 0) ? S1 : S2) + (size_t)pb * UU;

  __shared__ float qv[DM];
  __shared__ float wred[4][DM];
  const int t = threadIdx.x;
  if (t < DM) qv[t] = qrow[t];
  __syncthreads();

  const int r = chunk * 256 + t;   // exactly one row per thread
  const float4* rp = (const float4*)(rows + (size_t)r * DM);
  float rv[DM];
#pragma unroll
  for (int q = 0; q < 8; ++q) {
    float4 x = rp[q];
    rv[4 * q + 0] = x.x;
    rv[4 * q + 1] = x.y;
    rv[4 * q + 2] = x.z;
    rv[4 * q + 3] = x.w;
  }
  float dot = 0.f;
#pragma unroll
  for (int d = 0; d < DM; ++d) dot = fmaf(rv[d], qv[d], dot);
  const float w = __expf(dot) / den[r];

  const int lane = t & 63, wave = t >> 6;
#pragma unroll
  for (int d = 0; d < DM; ++d) {
    float vs = w * rv[d];
#pragma unroll
    for (int off = 32; off > 0; off >>= 1) vs += __shfl_down(vs, off, 64);
    if (lane == 0) wred[wave][d] = vs;
  }
  __syncthreads();
  if (t < DM) {
    float o = wred[0][t] + wred[1][t] + wred[2][t] + wred[3][t];
    OOpart[((size_t)pd * 8 + chunk) * DM + t] = o;
  }
}

// ---------------------------------------------------------------------------
// Stage 3 (1024 threads, one block):
//   OO[pd][d] = sum_c OOpart[pd][c][d]
//   Bi[b][p][dir*32+d] = OO[(p*16+b)*2+dir][d] * qrow[d]   (held in LDS)
//   Ci = tanh(Bi@fc1^T + fc1_b)@fc2^T ; alpha = softmax over batch;
//   CCA[b,:] = sum_k alpha[b,k] * Bi[b,k,:]
// ---------------------------------------------------------------------------
__global__ __launch_bounds__(1024) void stage3_head(
    const float* __restrict__ a, const float* __restrict__ v,
    const float* __restrict__ l, const float* __restrict__ OOpart,
    const float* __restrict__ fc1w, const float* __restrict__ fc1b,
    const float* __restrict__ fc2w, float* __restrict__ CCA) {
  const int t = threadIdx.x;
  __shared__ float BiL[NB * NP * 64];
  __shared__ float CiS[NB * NP];
  __shared__ float denomk[NP];

  // Phase A: Bi = (sum of OO partials) * qrow
#pragma unroll
  for (int iter = 0; iter < 3; ++iter) {
    int m = iter * 1024 + t;          // 0..3071
    int bk = m >> 6;                  // b*NP + p
    int h = m & 63;
    int b = bk / NP, p = bk - b * NP;
    int dir = h >> 5, hd = h & 31;
    const float* base = (dir == 0) ? ((p == 2) ? v : a) : ((p == 0) ? v : l);
    float q = base[(size_t)b * UU * DM + hd];
    int pd = (p * NB + b) * 2 + dir;
    float s = 0.f;
#pragma unroll
    for (int c = 0; c < 8; ++c) s += OOpart[((size_t)pd * 8 + c) * DM + hd];
    BiL[bk * 64 + h] = s * q;
  }
  __syncthreads();

  // Phase B: Ci[bk]; wave g handles bk = g + 16*iter
  const int h = t & 63;
  const int g = t >> 6;  // 0..15
#pragma unroll
  for (int iter = 0; iter < 3; ++iter) {
    int bk = g + 16 * iter;
    float x = fc1b[h];
#pragma unroll 8
    for (int c = 0; c < 64; ++c) x = fmaf(BiL[bk * 64 + c], fc1w[h * 64 + c], x);
    float vv = tanhf(x) * fc2w[h];
#pragma unroll
    for (int off = 32; off > 0; off >>= 1) vv += __shfl_down(vv, off, 64);
    if (h == 0) CiS[bk] = vv;
  }
  __syncthreads();

  if (t < NP) {
    float s = 0.f;
    for (int b = 0; b < NB; ++b) s += __expf(CiS[b * NP + t]);
    denomk[t] = s;
  }
  __syncthreads();

  // Phase C: CCA[b*64+h]; 16 groups x 64 threads = all 1024
  {
    int b = g;
    float s = 0.f;
#pragma unroll
    for (int k = 0; k < NP; ++k)
      s += __expf(CiS[b * NP + k]) / denomk[k] * BiL[(b * NP + k) * 64 + h];
    CCA[b * 64 + h] = s;
  }
}

// ---------------------------------------------------------------------------
// Stage 4: broadcast CCA[b,:] to out[b, u, :] for all u.  float4 stores.
// ---------------------------------------------------------------------------
__global__ __launch_bounds__(256) void stage4_bcast(
    const float* __restrict__ CCA, float4* __restrict__ out) {
  const int gid = blockIdx.x * 256 + threadIdx.x;  // 0 .. 524287 (float4 idx)
  const int c4 = gid & 15;        // 64 floats = 16 float4 per row
  const int b = gid >> 15;        // / (2048*16)
  const float4* cc = (const float4*)CCA;
  out[gid] = cc[b * 16 + c4];
}

extern "C" void kernel_launch(void* const* d_in, const int* in_sizes, int n_in,
                              void* d_out, int out_size, void* d_ws,
                              size_t ws_size, hipStream_t stream) {
  const float* a = (const float*)d_in[0];
  const float* v = (const float*)d_in[1];
  const float* l = (const float*)d_in[2];
  const float* fc1w = (const float*)d_in[3];
  const float* fc1b = (const float*)d_in[4];
  const float* fc2w = (const float*)d_in[5];
  float* out = (float*)d_out;

  // workspace layout (floats)
  float* S1 = (float*)d_ws;              // 3*16*2048
  float* S2 = S1 + NP * NB * UU;         // 3*16*2048
  float* OOpart = S2 + NP * NB * UU;     // 96*8*32 partial O sums (no init)
  float* CCA = OOpart + NP * NB * 2 * 8 * DM;  // 16*64

  // zero only the S1/S2 atomic accumulators
  hipMemsetAsync(d_ws, 0, (size_t)(2 * NP * NB * UU) * sizeof(float), stream);

  stage1_sums<<<dim3(UU / TB, UU / TB, NP * NB), 256, 0, stream>>>(a, v, l, S1,
                                                                   S2);
  stage2_O<<<dim3(NP * NB * 2 * 8), 256, 0, stream>>>(a, v, l, S1, S2, OOpart);
  stage3_head<<<dim3(1), 1024, 0, stream>>>(a, v, l, OOpart, fc1w, fc1b, fc2w,
                                            CCA);
  stage4_bcast<<<dim3(2048), 256, 0, stream>>>(CCA, (float4*)out);
}

// Round 6
// 219.554 us; speedup vs baseline: 1.4463x; 1.4463x over previous
//
#include <hip/hip_runtime.h>
#include <hip/hip_bf16.h>

#define UU 2048
#define DM 32
#define TB 128   // tile edge
#define NB 16    // batch
#define NP 3     // pairs

typedef short short8_t __attribute__((ext_vector_type(8)));
typedef float float4_t __attribute__((ext_vector_type(4)));

// split x into bf16 hi (truncate) + bf16 lo (truncate of remainder).
// hi+lo carries ~24 bits of mantissa; dropped lo*lo term in the dot is
// ~2^-16 relative -> dot abs err ~5e-4 vs absmax threshold 7e-2
// (validated: absmax 0.0039 in R3-R5).
__device__ inline void split8(const float4 x0, const float4 x1, short8_t& h,
                              short8_t& lo) {
  float xs[8] = {x0.x, x0.y, x0.z, x0.w, x1.x, x1.y, x1.z, x1.w};
#pragma unroll
  for (int i = 0; i < 8; ++i) {
    unsigned u = __float_as_uint(xs[i]);
    h[i] = (short)(u >> 16);
    float hif = __uint_as_float(u & 0xffff0000u);
    lo[i] = (short)(__float_as_uint(xs[i] - hif) >> 16);
  }
}

// ---------------------------------------------------------------------------
// Stage 0: pre-split all 3 modalities to bf16 hi/lo in global, laid out in
// MFMA fragment order: F[mod][b][group g=row/16][lane=lq*16+lm][8], where
// row = g*16+lm, col = lq*8+e. One 8-float unit per thread; reads and writes
// are both (permutation-within-1KB) coalesced. This removes split8 and all
// long register live-ranges from stage1 (the R4/R5 spill source).
// ---------------------------------------------------------------------------
__global__ __launch_bounds__(256) void stage0_split(
    const float* __restrict__ a, const float* __restrict__ v,
    const float* __restrict__ l, short8_t* __restrict__ Fh,
    short8_t* __restrict__ Fl) {
  const int u = blockIdx.x * 256 + threadIdx.x;  // 0 .. 3*16*2048*4-1
  const int e8 = u & 3;                          // k-quad (lq)
  const int row = (u >> 2) & (UU - 1);
  const int b = (u >> 13) & (NB - 1);
  const int m = u >> 17;                         // modality
  const float* src = ((m == 0) ? a : (m == 1) ? v : l) +
                     ((size_t)b * UU + row) * DM + e8 * 8;
  short8_t h, lo;
  split8(*(const float4*)src, *(const float4*)(src + 4), h, lo);
  const int g = row >> 4, lm = row & 15;
  const size_t d = ((size_t)(m * NB + b) * 128 + g) * 64 + e8 * 16 + lm;
  Fh[d] = h;
  Fl[d] = lo;
}

// ---------------------------------------------------------------------------
// Stage 1 (MFMA bf16x3): for each (pair, b) compute
//   S1[j] = sum_i exp(f1_i . f2_j),  S2[i] = sum_j exp(f1_i . f2_j)
// 128x128 region/block, 4 waves; wave w covers rows [w*32, w*32+32).
// Inputs come pre-split + fragment-ordered from stage0:
//   - B tile staging = contiguous 16KB copy (no VALU repack)
//   - A frags = 4 coalesced 16B loads/lane, consumed immediately (no spill)
//   - LDS 18KB, ds_read_b128 contiguous per wave (<=2-way banks = free)
// Per 16x16 tile: 3x mfma_f32_16x16x32_bf16 in two chains (hh | hl+lh).
// C/D layout: col=lane&15, row=(lane>>4)*4+reg  [m89-verified, R3-validated].
// ---------------------------------------------------------------------------
__global__ __launch_bounds__(256) void stage1_sums(
    const short8_t* __restrict__ Fh, const short8_t* __restrict__ Fl,
    float* __restrict__ S1, float* __restrict__ S2) {
  const int p = blockIdx.z >> 4;   // pair 0..2
  const int b = blockIdx.z & 15;   // batch
  const int m1 = (p == 2) ? 1 : 0;          // f1: p0,p1 -> a ; p2 -> v
  const int m2 = (p == 0) ? 1 : 2;          // f2: p0 -> v ; p1,p2 -> l
  const size_t base1 = (size_t)(m1 * NB + b) * 8192;  // short8 units
  const size_t base2 = (size_t)(m2 * NB + b) * 8192;
  const int i0 = blockIdx.y * TB;

  __shared__ short8_t BhS[512];   // 8KB  [g_local][lane] fragment order
  __shared__ short8_t BlS[512];   // 8KB
  __shared__ float ldsC[4][TB];   // 2KB

  const int t = threadIdx.x;
  const int lane = t & 63, w = t >> 6;
  const int lm = lane & 15, lq = lane >> 4;

  // Stage the B tile: pure contiguous copy (fragment order preserved).
  {
    const size_t off = base2 + (size_t)blockIdx.x * 512;
    BhS[t] = Fh[off + t];
    BhS[t + 256] = Fh[off + t + 256];
    BlS[t] = Fl[off + t];
    BlS[t + 256] = Fl[off + t + 256];
  }

  // A-frags: coalesced global loads straight into MFMA layout.
  short8_t a_h[2], a_l[2];
#pragma unroll
  for (int rt = 0; rt < 2; ++rt) {
    const size_t g = (size_t)blockIdx.y * 8 + w * 2 + rt;
    a_h[rt] = Fh[base1 + g * 64 + lane];
    a_l[rt] = Fl[base1 + g * 64 + lane];
  }
  __syncthreads();

  float rowp[2][4];
  float colp[8];
#pragma unroll
  for (int rt = 0; rt < 2; ++rt)
#pragma unroll
    for (int r = 0; r < 4; ++r) rowp[rt][r] = 0.f;
#pragma unroll
  for (int ct = 0; ct < 8; ++ct) colp[ct] = 0.f;

#pragma unroll
  for (int ct = 0; ct < 8; ++ct) {
    short8_t b_h = BhS[ct * 64 + lane];
    short8_t b_l = BlS[ct * 64 + lane];
#pragma unroll
    for (int rt = 0; rt < 2; ++rt) {
      float4_t c0 = {0.f, 0.f, 0.f, 0.f};
      float4_t c1 = {0.f, 0.f, 0.f, 0.f};
      c0 = __builtin_amdgcn_mfma_f32_16x16x32_bf16(a_h[rt], b_h, c0, 0, 0, 0);
      c1 = __builtin_amdgcn_mfma_f32_16x16x32_bf16(a_h[rt], b_l, c1, 0, 0, 0);
      c1 = __builtin_amdgcn_mfma_f32_16x16x32_bf16(a_l[rt], b_h, c1, 0, 0, 0);
      float e0 = __expf(c0[0] + c1[0]);
      float e1 = __expf(c0[1] + c1[1]);
      float e2 = __expf(c0[2] + c1[2]);
      float e3 = __expf(c0[3] + c1[3]);
      rowp[rt][0] += e0;
      rowp[rt][1] += e1;
      rowp[rt][2] += e2;
      rowp[rt][3] += e3;
      colp[ct] += (e0 + e1) + (e2 + e3);
    }
  }

  const size_t base = (size_t)(p * NB + b) * UU;

  // Row (i) sums: reduce across the 16 lanes of each quarter (cols 0..15)
#pragma unroll
  for (int rt = 0; rt < 2; ++rt)
#pragma unroll
    for (int r = 0; r < 4; ++r) {
      float vv = rowp[rt][r];
      vv += __shfl_xor(vv, 1, 64);
      vv += __shfl_xor(vv, 2, 64);
      vv += __shfl_xor(vv, 4, 64);
      vv += __shfl_xor(vv, 8, 64);
      if (lm == 0)
        atomicAdd(&S2[base + i0 + w * 32 + rt * 16 + lq * 4 + r], vv);
    }

  // Col (j) sums: reduce across quarters (rows), then across waves via LDS
#pragma unroll
  for (int ct = 0; ct < 8; ++ct) {
    float vv = colp[ct];
    vv += __shfl_xor(vv, 16, 64);
    vv += __shfl_xor(vv, 32, 64);
    if (lane < 16) ldsC[w][ct * 16 + lane] = vv;
  }
  __syncthreads();
  if (t < TB) {
    float s = ldsC[0][t] + ldsC[1][t] + ldsC[2][t] + ldsC[3][t];
    atomicAdd(&S1[base + (size_t)blockIdx.x * TB + t], s);
  }
}

// ---------------------------------------------------------------------------
// Stage 2: per (pair, b, dir, chunk-of-256-rows) compute the partial 32-vec
//   dir0: O1_part = sum_{j in chunk} exp(f1_0 . f2_j)/S1[j] * f2_j
//   dir1: O2_part = sum_{i in chunk} exp(f1_i . f2_0)/S2[i] * f1_i
// Plain store into OOpart[pd][chunk][32]. qrow scaling happens in stage3.
// ---------------------------------------------------------------------------
__global__ __launch_bounds__(256) void stage2_O(
    const float* __restrict__ a, const float* __restrict__ v,
    const float* __restrict__ l, const float* __restrict__ S1,
    const float* __restrict__ S2, float* __restrict__ OOpart) {
  const int idx = blockIdx.x;
  const int chunk = idx & 7;
  const int pd = idx >> 3;       // (pb, dir) flat
  const int dir = pd & 1;
  const int pb = pd >> 1;
  const int p = pb >> 4, b = pb & 15;
  const float* f1 = (p == 2) ? v : a;
  const float* f2 = (p == 0) ? v : l;
  f1 += (size_t)b * UU * DM;
  f2 += (size_t)b * UU * DM;
  const float* qrow = (dir == 0) ? f1 : f2;  // row 0 of the "query" side
  const float* rows = (dir == 0) ? f2 : f1;
  const float* den = ((dir == 0) ? S1 : S2) + (size_t)pb * UU;

  __shared__ float qv[DM];
  __shared__ float wred[4][DM];
  const int t = threadIdx.x;
  if (t < DM) qv[t] = qrow[t];
  __syncthreads();

  const int r = chunk * 256 + t;   // exactly one row per thread
  const float4* rp = (const float4*)(rows + (size_t)r * DM);
  float rv[DM];
#pragma unroll
  for (int q = 0; q < 8; ++q) {
    float4 x = rp[q];
    rv[4 * q + 0] = x.x;
    rv[4 * q + 1] = x.y;
    rv[4 * q + 2] = x.z;
    rv[4 * q + 3] = x.w;
  }
  float dot = 0.f;
#pragma unroll
  for (int d = 0; d < DM; ++d) dot = fmaf(rv[d], qv[d], dot);
  const float w = __expf(dot) / den[r];

  const int lane = t & 63, wave = t >> 6;
#pragma unroll
  for (int d = 0; d < DM; ++d) {
    float vs = w * rv[d];
#pragma unroll
    for (int off = 32; off > 0; off >>= 1) vs += __shfl_down(vs, off, 64);
    if (lane == 0) wred[wave][d] = vs;
  }
  __syncthreads();
  if (t < DM) {
    float o = wred[0][t] + wred[1][t] + wred[2][t] + wred[3][t];
    OOpart[((size_t)pd * 8 + chunk) * DM + t] = o;
  }
}

// ---------------------------------------------------------------------------
// Stage 3 (1024 threads, one block):
//   OO[pd][d] = sum_c OOpart[pd][c][d]
//   Bi[b][p][dir*32+d] = OO[(p*16+b)*2+dir][d] * qrow[d]   (held in LDS)
//   Ci = tanh(Bi@fc1^T + fc1_b)@fc2^T ; alpha = softmax over batch;
//   CCA[b,:] = sum_k alpha[b,k] * Bi[b,k,:]
// ---------------------------------------------------------------------------
__global__ __launch_bounds__(1024) void stage3_head(
    const float* __restrict__ a, const float* __restrict__ v,
    const float* __restrict__ l, const float* __restrict__ OOpart,
    const float* __restrict__ fc1w, const float* __restrict__ fc1b,
    const float* __restrict__ fc2w, float* __restrict__ CCA) {
  const int t = threadIdx.x;
  __shared__ float BiL[NB * NP * 64];
  __shared__ float CiS[NB * NP];
  __shared__ float denomk[NP];

  // Phase A: Bi = (sum of OO partials) * qrow
#pragma unroll
  for (int iter = 0; iter < 3; ++iter) {
    int m = iter * 1024 + t;          // 0..3071
    int bk = m >> 6;                  // b*NP + p
    int h = m & 63;
    int b = bk / NP, p = bk - b * NP;
    int dir = h >> 5, hd = h & 31;
    const float* base = (dir == 0) ? ((p == 2) ? v : a) : ((p == 0) ? v : l);
    float q = base[(size_t)b * UU * DM + hd];
    int pd = (p * NB + b) * 2 + dir;
    float s = 0.f;
#pragma unroll
    for (int c = 0; c < 8; ++c) s += OOpart[((size_t)pd * 8 + c) * DM + hd];
    BiL[bk * 64 + h] = s * q;
  }
  __syncthreads();

  // Phase B: Ci[bk]; wave g handles bk = g + 16*iter
  const int h = t & 63;
  const int g = t >> 6;  // 0..15
#pragma unroll
  for (int iter = 0; iter < 3; ++iter) {
    int bk = g + 16 * iter;
    float x = fc1b[h];
#pragma unroll 8
    for (int c = 0; c < 64; ++c) x = fmaf(BiL[bk * 64 + c], fc1w[h * 64 + c], x);
    float vv = tanhf(x) * fc2w[h];
#pragma unroll
    for (int off = 32; off > 0; off >>= 1) vv += __shfl_down(vv, off, 64);
    if (h == 0) CiS[bk] = vv;
  }
  __syncthreads();

  if (t < NP) {
    float s = 0.f;
    for (int b = 0; b < NB; ++b) s += __expf(CiS[b * NP + t]);
    denomk[t] = s;
  }
  __syncthreads();

  // Phase C: CCA[b*64+h]; 16 groups x 64 threads = all 1024
  {
    int b = g;
    float s = 0.f;
#pragma unroll
    for (int k = 0; k < NP; ++k)
      s += __expf(CiS[b * NP + k]) / denomk[k] * BiL[(b * NP + k) * 64 + h];
    CCA[b * 64 + h] = s;
  }
}

// ---------------------------------------------------------------------------
// Stage 4: broadcast CCA[b,:] to out[b, u, :] for all u.  float4 stores.
// ---------------------------------------------------------------------------
__global__ __launch_bounds__(256) void stage4_bcast(
    const float* __restrict__ CCA, float4* __restrict__ out) {
  const int gid = blockIdx.x * 256 + threadIdx.x;  // 0 .. 524287 (float4 idx)
  const int c4 = gid & 15;        // 64 floats = 16 float4 per row
  const int b = gid >> 15;        // / (2048*16)
  const float4* cc = (const float4*)CCA;
  out[gid] = cc[b * 16 + c4];
}

extern "C" void kernel_launch(void* const* d_in, const int* in_sizes, int n_in,
                              void* d_out, int out_size, void* d_ws,
                              size_t ws_size, hipStream_t stream) {
  const float* a = (const float*)d_in[0];
  const float* v = (const float*)d_in[1];
  const float* l = (const float*)d_in[2];
  const float* fc1w = (const float*)d_in[3];
  const float* fc1b = (const float*)d_in[4];
  const float* fc2w = (const float*)d_in[5];
  float* out = (float*)d_out;

  // workspace layout
  float* S1 = (float*)d_ws;                    // 98304 f
  float* S2 = S1 + NP * NB * UU;               // 98304 f
  float* OOpart = S2 + NP * NB * UU;           // 24576 f
  float* CCA = OOpart + NP * NB * 2 * 8 * DM;  // 1024 f
  // bf16 hi/lo pre-split arrays (fragment-ordered): 6.29 MB each
  short8_t* Fh = (short8_t*)((char*)d_ws + 888832);
  short8_t* Fl = Fh + (size_t)NP * NB * 128 * 64;  // 3*16*8192 short8 units

  // zero only the S1/S2 atomic accumulators
  hipMemsetAsync(d_ws, 0, (size_t)(2 * NP * NB * UU) * sizeof(float), stream);

  stage0_split<<<dim3(NP * NB * UU * 4 / 256), 256, 0, stream>>>(a, v, l, Fh,
                                                                 Fl);
  stage1_sums<<<dim3(UU / TB, UU / TB, NP * NB), 256, 0, stream>>>(Fh, Fl, S1,
                                                                   S2);
  stage2_O<<<dim3(NP * NB * 2 * 8), 256, 0, stream>>>(a, v, l, S1, S2, OOpart);
  stage3_head<<<dim3(1), 1024, 0, stream>>>(a, v, l, OOpart, fc1w, fc1b, fc2w,
                                            CCA);
  stage4_bcast<<<dim3(2048), 256, 0, stream>>>(CCA, (float4*)out);
}

// Round 7
// 206.351 us; speedup vs baseline: 1.5389x; 1.0640x over previous
//
#include <hip/hip_runtime.h>
#include <hip/hip_bf16.h>

#define UU 2048
#define DM 32
#define NB 16    // batch
#define NP 3     // pairs

typedef short short8_t __attribute__((ext_vector_type(8)));
typedef float float4_t __attribute__((ext_vector_type(4)));

// split x into bf16 hi (truncate) + bf16 lo (truncate of remainder).
// dropped lo*lo term ~2^-16 relative -> absmax 0.0039 (validated R3-R6)
// vs threshold 7e-2.
__device__ inline void split8(const float4 x0, const float4 x1, short8_t& h,
                              short8_t& lo) {
  float xs[8] = {x0.x, x0.y, x0.z, x0.w, x1.x, x1.y, x1.z, x1.w};
#pragma unroll
  for (int i = 0; i < 8; ++i) {
    unsigned u = __float_as_uint(xs[i]);
    h[i] = (short)(u >> 16);
    float hif = __uint_as_float(u & 0xffff0000u);
    lo[i] = (short)(__float_as_uint(xs[i] - hif) >> 16);
  }
}

// ---------------------------------------------------------------------------
// Stage 0: pre-split all 3 modalities to bf16 hi/lo in global, MFMA fragment
// order: F[mod][b][g=row/16][lane=kq*16+lm][8]  (row=g*16+lm, k=kq*8+e).
// Validated in R6: stage1 consumes with 0 bank conflicts, no repack VALU.
// ---------------------------------------------------------------------------
__global__ __launch_bounds__(256) void stage0_split(
    const float* __restrict__ a, const float* __restrict__ v,
    const float* __restrict__ l, short8_t* __restrict__ Fh,
    short8_t* __restrict__ Fl) {
  const int u = blockIdx.x * 256 + threadIdx.x;  // 0 .. 3*16*2048*4-1
  const int e8 = u & 3;                          // k-quad
  const int row = (u >> 2) & (UU - 1);
  const int b = (u >> 13) & (NB - 1);
  const int m = u >> 17;                         // modality
  const float* src = ((m == 0) ? a : (m == 1) ? v : l) +
                     ((size_t)b * UU + row) * DM + e8 * 8;
  short8_t h, lo;
  split8(*(const float4*)src, *(const float4*)(src + 4), h, lo);
  const int g = row >> 4, lm = row & 15;
  const size_t d = ((size_t)(m * NB + b) * 128 + g) * 64 + e8 * 16 + lm;
  Fh[d] = h;
  Fl[d] = lo;
}

// ---------------------------------------------------------------------------
// Stage 1 (MFMA bf16x3, row-band): block = (pair, b, 128-row i-band),
// streams all 2048 j in 16 chunks of 128 through LDS. 768 blocks = 3/CU.
// R6 failed with 12288 tiny blocks (48 MFMA each): occupancy 21% from
// per-block latency (startup loads, 3 barriers, atomic drain) that the
// little compute couldn't hide. Here each block runs 3072 MFMAs, A-frags
// are loaded once (16x reuse), and S2 rows are block-exact -> plain stores.
// Per 16x16 tile: 3x mfma_f32_16x16x32_bf16, two chains (hh | hl+lh).
// C/D layout: col=lane&15, row=(lane>>4)*4+reg  [m89-verified, validated].
// ---------------------------------------------------------------------------
__global__ __launch_bounds__(256) void stage1_sums(
    const short8_t* __restrict__ Fh, const short8_t* __restrict__ Fl,
    float* __restrict__ S1, float* __restrict__ S2) {
  const int p = blockIdx.z >> 4;   // pair 0..2
  const int b = blockIdx.z & 15;   // batch
  const int m1 = (p == 2) ? 1 : 0;          // f1: p0,p1 -> a ; p2 -> v
  const int m2 = (p == 0) ? 1 : 2;          // f2: p0 -> v ; p1,p2 -> l
  const size_t base1 = (size_t)(m1 * NB + b) * 8192;  // short8 units
  const size_t base2 = (size_t)(m2 * NB + b) * 8192;
  const int i0 = blockIdx.x * 128;

  __shared__ short8_t BhS[512];   // 8KB, fragment order [g_local][lane]
  __shared__ short8_t BlS[512];   // 8KB
  __shared__ float ldsC[4][128];  // 2KB

  const int t = threadIdx.x;
  const int lane = t & 63, w = t >> 6;
  const int lm = lane & 15, lq = lane >> 4;

  // A-frags: loaded ONCE, reused across all 16 j-chunks.
  short8_t a_h[2], a_l[2];
#pragma unroll
  for (int rt = 0; rt < 2; ++rt) {
    const size_t g = (size_t)blockIdx.x * 8 + w * 2 + rt;
    a_h[rt] = Fh[base1 + g * 64 + lane];
    a_l[rt] = Fl[base1 + g * 64 + lane];
  }

  float rowp[2][4];   // full row sums, accumulated over the whole j loop
#pragma unroll
  for (int rt = 0; rt < 2; ++rt)
#pragma unroll
    for (int r = 0; r < 4; ++r) rowp[rt][r] = 0.f;

  const size_t sbase = (size_t)(p * NB + b) * UU;

  for (int c = 0; c < 16; ++c) {
    __syncthreads();  // previous iteration's LDS reads complete
    {
      const size_t off = base2 + c * 512;
      BhS[t] = Fh[off + t];
      BhS[t + 256] = Fh[off + t + 256];
      BlS[t] = Fl[off + t];
      BlS[t + 256] = Fl[off + t + 256];
    }
    __syncthreads();

    float colp[8];
#pragma unroll
    for (int ct = 0; ct < 8; ++ct) colp[ct] = 0.f;

#pragma unroll
    for (int ct = 0; ct < 8; ++ct) {
      short8_t b_h = BhS[ct * 64 + lane];
      short8_t b_l = BlS[ct * 64 + lane];
#pragma unroll
      for (int rt = 0; rt < 2; ++rt) {
        float4_t c0 = {0.f, 0.f, 0.f, 0.f};
        float4_t c1 = {0.f, 0.f, 0.f, 0.f};
        c0 = __builtin_amdgcn_mfma_f32_16x16x32_bf16(a_h[rt], b_h, c0, 0, 0, 0);
        c1 = __builtin_amdgcn_mfma_f32_16x16x32_bf16(a_h[rt], b_l, c1, 0, 0, 0);
        c1 = __builtin_amdgcn_mfma_f32_16x16x32_bf16(a_l[rt], b_h, c1, 0, 0, 0);
        float e0 = __expf(c0[0] + c1[0]);
        float e1 = __expf(c0[1] + c1[1]);
        float e2 = __expf(c0[2] + c1[2]);
        float e3 = __expf(c0[3] + c1[3]);
        rowp[rt][0] += e0;
        rowp[rt][1] += e1;
        rowp[rt][2] += e2;
        rowp[rt][3] += e3;
        colp[ct] += (e0 + e1) + (e2 + e3);
      }
    }

    // Col (j) sums for this chunk: reduce across row-quarters, then waves.
#pragma unroll
    for (int ct = 0; ct < 8; ++ct) {
      float vv = colp[ct];
      vv += __shfl_xor(vv, 16, 64);
      vv += __shfl_xor(vv, 32, 64);
      if (lane < 16) ldsC[w][ct * 16 + lane] = vv;
    }
    __syncthreads();
    if (t < 128) {
      float s = ldsC[0][t] + ldsC[1][t] + ldsC[2][t] + ldsC[3][t];
      atomicAdd(&S1[sbase + c * 128 + t], s);
    }
  }

  // Row (i) sums are complete (all j seen) -> plain stores, no atomics.
#pragma unroll
  for (int rt = 0; rt < 2; ++rt)
#pragma unroll
    for (int r = 0; r < 4; ++r) {
      float vv = rowp[rt][r];
      vv += __shfl_xor(vv, 1, 64);
      vv += __shfl_xor(vv, 2, 64);
      vv += __shfl_xor(vv, 4, 64);
      vv += __shfl_xor(vv, 8, 64);
      if (lm == 0)
        S2[sbase + i0 + w * 32 + rt * 16 + lq * 4 + r] = vv;
    }
}

// ---------------------------------------------------------------------------
// Stage 2: per (pair, b, dir, chunk-of-256-rows) compute the partial 32-vec
//   dir0: O1_part = sum_{j in chunk} exp(f1_0 . f2_j)/S1[j] * f2_j
//   dir1: O2_part = sum_{i in chunk} exp(f1_i . f2_0)/S2[i] * f1_i
// Plain store into OOpart[pd][chunk][32]. qrow scaling happens in stage3.
// ---------------------------------------------------------------------------
__global__ __launch_bounds__(256) void stage2_O(
    const float* __restrict__ a, const float* __restrict__ v,
    const float* __restrict__ l, const float* __restrict__ S1,
    const float* __restrict__ S2, float* __restrict__ OOpart) {
  const int idx = blockIdx.x;
  const int chunk = idx & 7;
  const int pd = idx >> 3;       // (pb, dir) flat
  const int dir = pd & 1;
  const int pb = pd >> 1;
  const int p = pb >> 4, b = pb & 15;
  const float* f1 = (p == 2) ? v : a;
  const float* f2 = (p == 0) ? v : l;
  f1 += (size_t)b * UU * DM;
  f2 += (size_t)b * UU * DM;
  const float* qrow = (dir == 0) ? f1 : f2;  // row 0 of the "query" side
  const float* rows = (dir == 0) ? f2 : f1;
  const float* den = ((dir == 0) ? S1 : S2) + (size_t)pb * UU;

  __shared__ float qv[DM];
  __shared__ float wred[4][DM];
  const int t = threadIdx.x;
  if (t < DM) qv[t] = qrow[t];
  __syncthreads();

  const int r = chunk * 256 + t;   // exactly one row per thread
  const float4* rp = (const float4*)(rows + (size_t)r * DM);
  float rv[DM];
#pragma unroll
  for (int q = 0; q < 8; ++q) {
    float4 x = rp[q];
    rv[4 * q + 0] = x.x;
    rv[4 * q + 1] = x.y;
    rv[4 * q + 2] = x.z;
    rv[4 * q + 3] = x.w;
  }
  float dot = 0.f;
#pragma unroll
  for (int d = 0; d < DM; ++d) dot = fmaf(rv[d], qv[d], dot);
  const float w = __expf(dot) / den[r];

  const int lane = t & 63, wave = t >> 6;
#pragma unroll
  for (int d = 0; d < DM; ++d) {
    float vs = w * rv[d];
#pragma unroll
    for (int off = 32; off > 0; off >>= 1) vs += __shfl_down(vs, off, 64);
    if (lane == 0) wred[wave][d] = vs;
  }
  __syncthreads();
  if (t < DM) {
    float o = wred[0][t] + wred[1][t] + wred[2][t] + wred[3][t];
    OOpart[((size_t)pd * 8 + chunk) * DM + t] = o;
  }
}

// ---------------------------------------------------------------------------
// Stage 3 (1024 threads, one block):
//   OO[pd][d] = sum_c OOpart[pd][c][d]
//   Bi[b][p][dir*32+d] = OO[(p*16+b)*2+dir][d] * qrow[d]   (held in LDS)
//   Ci = tanh(Bi@fc1^T + fc1_b)@fc2^T ; alpha = softmax over batch;
//   CCA[b,:] = sum_k alpha[b,k] * Bi[b,k,:]
// ---------------------------------------------------------------------------
__global__ __launch_bounds__(1024) void stage3_head(
    const float* __restrict__ a, const float* __restrict__ v,
    const float* __restrict__ l, const float* __restrict__ OOpart,
    const float* __restrict__ fc1w, const float* __restrict__ fc1b,
    const float* __restrict__ fc2w, float* __restrict__ CCA) {
  const int t = threadIdx.x;
  __shared__ float BiL[NB * NP * 64];
  __shared__ float CiS[NB * NP];
  __shared__ float denomk[NP];

  // Phase A: Bi = (sum of OO partials) * qrow
#pragma unroll
  for (int iter = 0; iter < 3; ++iter) {
    int m = iter * 1024 + t;          // 0..3071
    int bk = m >> 6;                  // b*NP + p
    int h = m & 63;
    int b = bk / NP, p = bk - b * NP;
    int dir = h >> 5, hd = h & 31;
    const float* base = (dir == 0) ? ((p == 2) ? v : a) : ((p == 0) ? v : l);
    float q = base[(size_t)b * UU * DM + hd];
    int pd = (p * NB + b) * 2 + dir;
    float s = 0.f;
#pragma unroll
    for (int c = 0; c < 8; ++c) s += OOpart[((size_t)pd * 8 + c) * DM + hd];
    BiL[bk * 64 + h] = s * q;
  }
  __syncthreads();

  // Phase B: Ci[bk]; wave g handles bk = g + 16*iter
  const int h = t & 63;
  const int g = t >> 6;  // 0..15
#pragma unroll
  for (int iter = 0; iter < 3; ++iter) {
    int bk = g + 16 * iter;
    float x = fc1b[h];
#pragma unroll 8
    for (int c = 0; c < 64; ++c) x = fmaf(BiL[bk * 64 + c], fc1w[h * 64 + c], x);
    float vv = tanhf(x) * fc2w[h];
#pragma unroll
    for (int off = 32; off > 0; off >>= 1) vv += __shfl_down(vv, off, 64);
    if (h == 0) CiS[bk] = vv;
  }
  __syncthreads();

  if (t < NP) {
    float s = 0.f;
    for (int b = 0; b < NB; ++b) s += __expf(CiS[b * NP + t]);
    denomk[t] = s;
  }
  __syncthreads();

  // Phase C: CCA[b*64+h]; 16 groups x 64 threads = all 1024
  {
    int b = g;
    float s = 0.f;
#pragma unroll
    for (int k = 0; k < NP; ++k)
      s += __expf(CiS[b * NP + k]) / denomk[k] * BiL[(b * NP + k) * 64 + h];
    CCA[b * 64 + h] = s;
  }
}

// ---------------------------------------------------------------------------
// Stage 4: broadcast CCA[b,:] to out[b, u, :] for all u.  float4 stores.
// ---------------------------------------------------------------------------
__global__ __launch_bounds__(256) void stage4_bcast(
    const float* __restrict__ CCA, float4* __restrict__ out) {
  const int gid = blockIdx.x * 256 + threadIdx.x;  // 0 .. 524287 (float4 idx)
  const int c4 = gid & 15;        // 64 floats = 16 float4 per row
  const int b = gid >> 15;        // / (2048*16)
  const float4* cc = (const float4*)CCA;
  out[gid] = cc[b * 16 + c4];
}

extern "C" void kernel_launch(void* const* d_in, const int* in_sizes, int n_in,
                              void* d_out, int out_size, void* d_ws,
                              size_t ws_size, hipStream_t stream) {
  const float* a = (const float*)d_in[0];
  const float* v = (const float*)d_in[1];
  const float* l = (const float*)d_in[2];
  const float* fc1w = (const float*)d_in[3];
  const float* fc1b = (const float*)d_in[4];
  const float* fc2w = (const float*)d_in[5];
  float* out = (float*)d_out;

  // workspace layout
  float* S1 = (float*)d_ws;                    // 98304 f (atomic, memset)
  float* S2 = S1 + NP * NB * UU;               // 98304 f (plain stores)
  float* OOpart = S2 + NP * NB * UU;           // 24576 f
  float* CCA = OOpart + NP * NB * 2 * 8 * DM;  // 1024 f
  // bf16 hi/lo pre-split arrays (fragment-ordered): 6.29 MB each
  short8_t* Fh = (short8_t*)((char*)d_ws + 888832);
  short8_t* Fl = Fh + (size_t)NP * NB * 128 * 64;  // 3*16*8192 short8 units

  // zero only S1 (S2 is written with plain stores now)
  hipMemsetAsync(d_ws, 0, (size_t)(NP * NB * UU) * sizeof(float), stream);

  stage0_split<<<dim3(NP * NB * UU * 4 / 256), 256, 0, stream>>>(a, v, l, Fh,
                                                                 Fl);
  stage1_sums<<<dim3(UU / 128, 1, NP * NB), 256, 0, stream>>>(Fh, Fl, S1, S2);
  stage2_O<<<dim3(NP * NB * 2 * 8), 256, 0, stream>>>(a, v, l, S1, S2, OOpart);
  stage3_head<<<dim3(1), 1024, 0, stream>>>(a, v, l, OOpart, fc1w, fc1b, fc2w,
                                            CCA);
  stage4_bcast<<<dim3(2048), 256, 0, stream>>>(CCA, (float4*)out);
}

// Round 8
// 192.523 us; speedup vs baseline: 1.6494x; 1.0718x over previous
//
#include <hip/hip_runtime.h>
#include <hip/hip_bf16.h>

#define UU 2048
#define DM 32
#define NB 16    // batch
#define NP 3     // pairs

typedef short short8_t __attribute__((ext_vector_type(8)));
typedef float float4_t __attribute__((ext_vector_type(4)));

// split (SCALE*x) into bf16 hi + bf16 lo. SCALE = sqrt(log2(e)) so that
// dot(hi+lo, hi+lo) = log2(e)*dot(x,y): stage1 can use raw v_exp_f32
// (exp2) with no per-element multiply. Dropped lo*lo ~2^-16 relative
// (absmax 0.0039 validated R3-R7 vs threshold 7e-2).
#define SCALE 1.2011224087864498f

__device__ inline void split8(const float4 x0, const float4 x1, short8_t& h,
                              short8_t& lo) {
  float xs[8] = {x0.x, x0.y, x0.z, x0.w, x1.x, x1.y, x1.z, x1.w};
#pragma unroll
  for (int i = 0; i < 8; ++i) {
    float x = xs[i] * SCALE;
    unsigned u = __float_as_uint(x);
    h[i] = (short)(u >> 16);
    float hif = __uint_as_float(u & 0xffff0000u);
    lo[i] = (short)(__float_as_uint(x - hif) >> 16);
  }
}

// ---------------------------------------------------------------------------
// Stage 0: pre-split all 3 modalities (scaled by sqrt(log2 e)) to bf16 hi/lo
// in MFMA fragment order: F[mod][b][g=row/16][lane=kq*16+lm][8].
// ---------------------------------------------------------------------------
__global__ __launch_bounds__(256) void stage0_split(
    const float* __restrict__ a, const float* __restrict__ v,
    const float* __restrict__ l, short8_t* __restrict__ Fh,
    short8_t* __restrict__ Fl) {
  const int u = blockIdx.x * 256 + threadIdx.x;  // 0 .. 3*16*2048*4-1
  const int e8 = u & 3;                          // k-quad
  const int row = (u >> 2) & (UU - 1);
  const int b = (u >> 13) & (NB - 1);
  const int m = u >> 17;                         // modality
  const float* src = ((m == 0) ? a : (m == 1) ? v : l) +
                     ((size_t)b * UU + row) * DM + e8 * 8;
  short8_t h, lo;
  split8(*(const float4*)src, *(const float4*)(src + 4), h, lo);
  const int g = row >> 4, lm = row & 15;
  const size_t d = ((size_t)(m * NB + b) * 128 + g) * 64 + e8 * 16 + lm;
  Fh[d] = h;
  Fl[d] = lo;
}

// ---------------------------------------------------------------------------
// Stage 1 (MFMA bf16x3, row-band, 1-barrier pipeline): block = (pair, b,
// 128-row i-band), streams 2048 j in 16 chunks. 768 blocks = 3/CU.
// R7 stalled (VALU 46%, occ 17%): 3 barriers/chunk and the barrier vmcnt(0)
// drain included the previous chunk's contended device-scope atomicAdd
// (16 blocks x same 512B S1 region, cross-XCD, every chunk). Now:
//   - double-buffered B tiles -> ONE barrier per chunk
//   - col partials accumulate in LDS via ds_add_f32 (block-local)
//   - the 2048 global atomics fire once at block end, off the barrier path
//   - 3-MFMA single-accumulator chain; exp = raw v_exp_f32 (pre-scaled)
// C/D layout: col=lane&15, row=(lane>>4)*4+reg  [m89-verified, validated].
// ---------------------------------------------------------------------------
__global__ __launch_bounds__(256) void stage1_sums(
    const short8_t* __restrict__ Fh, const short8_t* __restrict__ Fl,
    float* __restrict__ S1, float* __restrict__ S2) {
  const int p = blockIdx.z >> 4;   // pair 0..2
  const int b = blockIdx.z & 15;   // batch
  const int m1 = (p == 2) ? 1 : 0;          // f1: p0,p1 -> a ; p2 -> v
  const int m2 = (p == 0) ? 1 : 2;          // f2: p0 -> v ; p1,p2 -> l
  const size_t base1 = (size_t)(m1 * NB + b) * 8192;  // short8 units
  const size_t base2 = (size_t)(m2 * NB + b) * 8192;
  const int i0 = blockIdx.x * 128;

  __shared__ short8_t BhS[2][512];  // 16KB double-buffered B hi
  __shared__ short8_t BlS[2][512];  // 16KB double-buffered B lo
  __shared__ float ldsS1[16 * 128]; // 8KB block-local col sums

  const int t = threadIdx.x;
  const int lane = t & 63, w = t >> 6;
  const int lm = lane & 15, lq = lane >> 4;

  // zero the LDS col accumulator
#pragma unroll
  for (int k = 0; k < 8; ++k) ldsS1[t + k * 256] = 0.f;

  // A-frags: loaded ONCE, reused across all 16 j-chunks.
  short8_t a_h[2], a_l[2];
#pragma unroll
  for (int rt = 0; rt < 2; ++rt) {
    const size_t g = (size_t)blockIdx.x * 8 + w * 2 + rt;
    a_h[rt] = Fh[base1 + g * 64 + lane];
    a_l[rt] = Fl[base1 + g * 64 + lane];
  }

  // preload chunk 0 into buffer 0
  BhS[0][t] = Fh[base2 + t];
  BhS[0][t + 256] = Fh[base2 + t + 256];
  BlS[0][t] = Fl[base2 + t];
  BlS[0][t + 256] = Fl[base2 + t + 256];

  float rowp[2][4];
#pragma unroll
  for (int rt = 0; rt < 2; ++rt)
#pragma unroll
    for (int r = 0; r < 4; ++r) rowp[rt][r] = 0.f;

  __syncthreads();

  for (int c = 0; c < 16; ++c) {
    const int cur = c & 1, nxt = cur ^ 1;
    // issue next chunk's global loads early (latency hidden by compute)
    short8_t nh0, nh1, nl0, nl1;
    if (c < 15) {
      const size_t off = base2 + (c + 1) * 512;
      nh0 = Fh[off + t];
      nh1 = Fh[off + t + 256];
      nl0 = Fl[off + t];
      nl1 = Fl[off + t + 256];
    }

    float colp[8];
#pragma unroll
    for (int ct = 0; ct < 8; ++ct) colp[ct] = 0.f;

#pragma unroll
    for (int ct = 0; ct < 8; ++ct) {
      short8_t b_h = BhS[cur][ct * 64 + lane];
      short8_t b_l = BlS[cur][ct * 64 + lane];
#pragma unroll
      for (int rt = 0; rt < 2; ++rt) {
        float4_t cc = {0.f, 0.f, 0.f, 0.f};
        cc = __builtin_amdgcn_mfma_f32_16x16x32_bf16(a_l[rt], b_h, cc, 0, 0, 0);
        cc = __builtin_amdgcn_mfma_f32_16x16x32_bf16(a_h[rt], b_l, cc, 0, 0, 0);
        cc = __builtin_amdgcn_mfma_f32_16x16x32_bf16(a_h[rt], b_h, cc, 0, 0, 0);
        float e0 = __builtin_amdgcn_exp2f(cc[0]);
        float e1 = __builtin_amdgcn_exp2f(cc[1]);
        float e2 = __builtin_amdgcn_exp2f(cc[2]);
        float e3 = __builtin_amdgcn_exp2f(cc[3]);
        rowp[rt][0] += e0;
        rowp[rt][1] += e1;
        rowp[rt][2] += e2;
        rowp[rt][3] += e3;
        colp[ct] += (e0 + e1) + (e2 + e3);
      }
    }

    // col partials: reduce across the 4 row-quarters, then LDS-atomic
    // accumulate (block-local ds_add_f32, cross-wave safe, no barrier).
#pragma unroll
    for (int ct = 0; ct < 8; ++ct) {
      float vv = colp[ct];
      vv += __shfl_xor(vv, 16, 64);
      vv += __shfl_xor(vv, 32, 64);
      if (lane < 16) atomicAdd(&ldsS1[c * 128 + ct * 16 + lane], vv);
    }

    // stage next chunk into the other buffer
    if (c < 15) {
      BhS[nxt][t] = nh0;
      BhS[nxt][t + 256] = nh1;
      BlS[nxt][t] = nl0;
      BlS[nxt][t + 256] = nl1;
    }
    __syncthreads();  // the single per-chunk barrier
  }

  const size_t sbase = (size_t)(p * NB + b) * UU;

  // Global col-sum atomics: once per block, off the chunk-loop barrier path.
  if (t < 128) {
#pragma unroll
    for (int c = 0; c < 16; ++c)
      atomicAdd(&S1[sbase + c * 128 + t], ldsS1[c * 128 + t]);
  }

  // Row sums complete (all j seen) -> plain stores.
#pragma unroll
  for (int rt = 0; rt < 2; ++rt)
#pragma unroll
    for (int r = 0; r < 4; ++r) {
      float vv = rowp[rt][r];
      vv += __shfl_xor(vv, 1, 64);
      vv += __shfl_xor(vv, 2, 64);
      vv += __shfl_xor(vv, 4, 64);
      vv += __shfl_xor(vv, 8, 64);
      if (lm == 0) S2[sbase + i0 + w * 32 + rt * 16 + lq * 4 + r] = vv;
    }
}

// ---------------------------------------------------------------------------
// Stage 2: per (pair, b, dir, chunk-of-256-rows) compute the partial 32-vec
//   dir0: O1_part = sum_{j in chunk} exp(f1_0 . f2_j)/S1[j] * f2_j
//   dir1: O2_part = sum_{i in chunk} exp(f1_i . f2_0)/S2[i] * f1_i
// Plain store into OOpart[pd][chunk][32]. qrow scaling happens in stage3.
// ---------------------------------------------------------------------------
__global__ __launch_bounds__(256) void stage2_O(
    const float* __restrict__ a, const float* __restrict__ v,
    const float* __restrict__ l, const float* __restrict__ S1,
    const float* __restrict__ S2, float* __restrict__ OOpart) {
  const int idx = blockIdx.x;
  const int chunk = idx & 7;
  const int pd = idx >> 3;       // (pb, dir) flat
  const int dir = pd & 1;
  const int pb = pd >> 1;
  const int p = pb >> 4, b = pb & 15;
  const float* f1 = (p == 2) ? v : a;
  const float* f2 = (p == 0) ? v : l;
  f1 += (size_t)b * UU * DM;
  f2 += (size_t)b * UU * DM;
  const float* qrow = (dir == 0) ? f1 : f2;  // row 0 of the "query" side
  const float* rows = (dir == 0) ? f2 : f1;
  const float* den = ((dir == 0) ? S1 : S2) + (size_t)pb * UU;

  __shared__ float qv[DM];
  __shared__ float wred[4][DM];
  const int t = threadIdx.x;
  if (t < DM) qv[t] = qrow[t];
  __syncthreads();

  const int r = chunk * 256 + t;   // exactly one row per thread
  const float4* rp = (const float4*)(rows + (size_t)r * DM);
  float rv[DM];
#pragma unroll
  for (int q = 0; q < 8; ++q) {
    float4 x = rp[q];
    rv[4 * q + 0] = x.x;
    rv[4 * q + 1] = x.y;
    rv[4 * q + 2] = x.z;
    rv[4 * q + 3] = x.w;
  }
  float dot = 0.f;
#pragma unroll
  for (int d = 0; d < DM; ++d) dot = fmaf(rv[d], qv[d], dot);
  const float w = __expf(dot) / den[r];

  const int lane = t & 63, wave = t >> 6;
#pragma unroll
  for (int d = 0; d < DM; ++d) {
    float vs = w * rv[d];
#pragma unroll
    for (int off = 32; off > 0; off >>= 1) vs += __shfl_down(vs, off, 64);
    if (lane == 0) wred[wave][d] = vs;
  }
  __syncthreads();
  if (t < DM) {
    float o = wred[0][t] + wred[1][t] + wred[2][t] + wred[3][t];
    OOpart[((size_t)pd * 8 + chunk) * DM + t] = o;
  }
}

// ---------------------------------------------------------------------------
// Stage 3 (1024 threads, one block):
//   OO[pd][d] = sum_c OOpart[pd][c][d]
//   Bi[b][p][dir*32+d] = OO[(p*16+b)*2+dir][d] * qrow[d]   (held in LDS)
//   Ci = tanh(Bi@fc1^T + fc1_b)@fc2^T ; alpha = softmax over batch;
//   CCA[b,:] = sum_k alpha[b,k] * Bi[b,k,:]
// ---------------------------------------------------------------------------
__global__ __launch_bounds__(1024) void stage3_head(
    const float* __restrict__ a, const float* __restrict__ v,
    const float* __restrict__ l, const float* __restrict__ OOpart,
    const float* __restrict__ fc1w, const float* __restrict__ fc1b,
    const float* __restrict__ fc2w, float* __restrict__ CCA) {
  const int t = threadIdx.x;
  __shared__ float BiL[NB * NP * 64];
  __shared__ float CiS[NB * NP];
  __shared__ float denomk[NP];

  // Phase A: Bi = (sum of OO partials) * qrow
#pragma unroll
  for (int iter = 0; iter < 3; ++iter) {
    int m = iter * 1024 + t;          // 0..3071
    int bk = m >> 6;                  // b*NP + p
    int h = m & 63;
    int b = bk / NP, p = bk - b * NP;
    int dir = h >> 5, hd = h & 31;
    const float* base = (dir == 0) ? ((p == 2) ? v : a) : ((p == 0) ? v : l);
    float q = base[(size_t)b * UU * DM + hd];
    int pd = (p * NB + b) * 2 + dir;
    float s = 0.f;
#pragma unroll
    for (int c = 0; c < 8; ++c) s += OOpart[((size_t)pd * 8 + c) * DM + hd];
    BiL[bk * 64 + h] = s * q;
  }
  __syncthreads();

  // Phase B: Ci[bk]; wave g handles bk = g + 16*iter
  const int h = t & 63;
  const int g = t >> 6;  // 0..15
#pragma unroll
  for (int iter = 0; iter < 3; ++iter) {
    int bk = g + 16 * iter;
    float x = fc1b[h];
#pragma unroll 8
    for (int c = 0; c < 64; ++c) x = fmaf(BiL[bk * 64 + c], fc1w[h * 64 + c], x);
    float vv = tanhf(x) * fc2w[h];
#pragma unroll
    for (int off = 32; off > 0; off >>= 1) vv += __shfl_down(vv, off, 64);
    if (h == 0) CiS[bk] = vv;
  }
  __syncthreads();

  if (t < NP) {
    float s = 0.f;
    for (int b = 0; b < NB; ++b) s += __expf(CiS[b * NP + t]);
    denomk[t] = s;
  }
  __syncthreads();

  // Phase C: CCA[b*64+h]; 16 groups x 64 threads = all 1024
  {
    int b = g;
    float s = 0.f;
#pragma unroll
    for (int k = 0; k < NP; ++k)
      s += __expf(CiS[b * NP + k]) / denomk[k] * BiL[(b * NP + k) * 64 + h];
    CCA[b * 64 + h] = s;
  }
}

// ---------------------------------------------------------------------------
// Stage 4: broadcast CCA[b,:] to out[b, u, :] for all u.  float4 stores.
// ---------------------------------------------------------------------------
__global__ __launch_bounds__(256) void stage4_bcast(
    const float* __restrict__ CCA, float4* __restrict__ out) {
  const int gid = blockIdx.x * 256 + threadIdx.x;  // 0 .. 524287 (float4 idx)
  const int c4 = gid & 15;        // 64 floats = 16 float4 per row
  const int b = gid >> 15;        // / (2048*16)
  const float4* cc = (const float4*)CCA;
  out[gid] = cc[b * 16 + c4];
}

extern "C" void kernel_launch(void* const* d_in, const int* in_sizes, int n_in,
                              void* d_out, int out_size, void* d_ws,
                              size_t ws_size, hipStream_t stream) {
  const float* a = (const float*)d_in[0];
  const float* v = (const float*)d_in[1];
  const float* l = (const float*)d_in[2];
  const float* fc1w = (const float*)d_in[3];
  const float* fc1b = (const float*)d_in[4];
  const float* fc2w = (const float*)d_in[5];
  float* out = (float*)d_out;

  // workspace layout
  float* S1 = (float*)d_ws;                    // 98304 f (atomic, memset)
  float* S2 = S1 + NP * NB * UU;               // 98304 f (plain stores)
  float* OOpart = S2 + NP * NB * UU;           // 24576 f
  float* CCA = OOpart + NP * NB * 2 * 8 * DM;  // 1024 f
  // bf16 hi/lo pre-split arrays (fragment-ordered): 6.29 MB each
  short8_t* Fh = (short8_t*)((char*)d_ws + 888832);
  short8_t* Fl = Fh + (size_t)NP * NB * 128 * 64;  // 3*16*8192 short8 units

  // zero only S1 (S2/OOpart/CCA are written with plain stores)
  hipMemsetAsync(d_ws, 0, (size_t)(NP * NB * UU) * sizeof(float), stream);

  stage0_split<<<dim3(NP * NB * UU * 4 / 256), 256, 0, stream>>>(a, v, l, Fh,
                                                                 Fl);
  stage1_sums<<<dim3(UU / 128, 1, NP * NB), 256, 0, stream>>>(Fh, Fl, S1, S2);
  stage2_O<<<dim3(NP * NB * 2 * 8), 256, 0, stream>>>(a, v, l, S1, S2, OOpart);
  stage3_head<<<dim3(1), 1024, 0, stream>>>(a, v, l, OOpart, fc1w, fc1b, fc2w,
                                            CCA);
  stage4_bcast<<<dim3(2048), 256, 0, stream>>>(CCA, (float4*)out);
}